// Round 10
// baseline (259.368 us; speedup 1.0000x reference)
//
#include <hip/hip_runtime.h>

#define N_CLAUSES 50000
#define FEAT_DIM 64
#define EMBED_DIM 128
#define NUM_QUEUES 8
#define NUM_STEPS 2048
#define ENTROPY_COEF 0.1f

typedef unsigned int v4u __attribute__((ext_vector_type(4)));

// ---------------- workspace layout (float units) ----------------
#define WS_LOGITS 0                 // [8][50000]
#define WS_ROWMAX 400000            // [8] int-encoded max
#define WS_K2T    400008            // [128][8]
#define WS_CQ     401032            // [8]
#define WS_W1T    401040            // [128][64]
#define WS_LOSS   409232            // [2048]

#define LDS_BYTES 100000            // 50000 x u16 (bf16 e values)

// order-preserving float<->int encode for atomicMax on signed int
__device__ inline int enc_f(float f) {
  int b = __float_as_int(f);
  return b >= 0 ? b : (b ^ 0x7FFFFFFF);
}
__device__ inline float dec_f(int k) {
  return __int_as_float(k >= 0 ? k : (k ^ 0x7FFFFFFF));
}

__global__ __launch_bounds__(1024) void k_prep(const float* __restrict__ W1,
    const float* __restrict__ b2, const float* __restrict__ W2,
    const float* __restrict__ keys, float* __restrict__ W1T,
    float* __restrict__ K2T, float* __restrict__ cq, int* __restrict__ rowmax_i) {
  int tid = threadIdx.x;
  {
    int q = tid >> 7, j = tid & 127;
    float a = 0.f;
    for (int e = 0; e < EMBED_DIM; ++e)
      a = fmaf(W2[j * EMBED_DIM + e], keys[q * EMBED_DIM + e], a);
    K2T[j * 8 + q] = a;
  }
  if (tid < NUM_QUEUES) {
    float a = 0.f;
    for (int e = 0; e < EMBED_DIM; ++e)
      a = fmaf(b2[e], keys[tid * EMBED_DIM + e], a);
    cq[tid] = a;
    rowmax_i[tid] = (int)0x80000000;   // INT_MIN
  }
  for (int i = tid; i < FEAT_DIM * EMBED_DIM; i += 1024) {
    int j = i >> 6, f = i & 63;
    W1T[j * 64 + f] = W1[f * EMBED_DIM + j];
  }
}

// logits[q][n] = relu(fv[n]@W1 + b1) . K2[q] + cq[q]; fused per-queue row-max.
__global__ __launch_bounds__(256) void k_logits(const float* __restrict__ fv,
    const float* __restrict__ b1, const float* __restrict__ W1T,
    const float* __restrict__ K2T, const float* __restrict__ cq,
    float* __restrict__ logits, int* __restrict__ rowmax_i) {
  int t = threadIdx.x;
  int n = blockIdx.x * 256 + t;
  bool act = n < N_CLAUSES;
  int nn = act ? n : (N_CLAUSES - 1);
  float r[FEAT_DIM];
  const float4* fp = (const float4*)(fv + (size_t)nn * FEAT_DIM);
#pragma unroll
  for (int i = 0; i < FEAT_DIM / 4; ++i) {
    float4 v = fp[i];
    r[4 * i] = v.x; r[4 * i + 1] = v.y; r[4 * i + 2] = v.z; r[4 * i + 3] = v.w;
  }
  float acc[NUM_QUEUES];
#pragma unroll
  for (int q = 0; q < NUM_QUEUES; ++q) acc[q] = cq[q];
#pragma unroll 4
  for (int j = 0; j < EMBED_DIM; ++j) {
    const float* w = W1T + j * 64;   // wave-uniform -> scalar loads
    float t0 = 0.f, t1 = 0.f, t2 = 0.f, t3 = 0.f;
#pragma unroll
    for (int f = 0; f < FEAT_DIM; f += 4) {
      t0 = fmaf(r[f],     w[f],     t0);
      t1 = fmaf(r[f + 1], w[f + 1], t1);
      t2 = fmaf(r[f + 2], w[f + 2], t2);
      t3 = fmaf(r[f + 3], w[f + 3], t3);
    }
    float tt = fmaxf((t0 + t1) + (t2 + t3) + b1[j], 0.f);
    const float* k2 = K2T + j * 8;
#pragma unroll
    for (int q = 0; q < NUM_QUEUES; ++q) acc[q] = fmaf(tt, k2[q], acc[q]);
  }
  if (act) {
#pragma unroll
    for (int q = 0; q < NUM_QUEUES; ++q)
      logits[(size_t)q * N_CLAUSES + n] = acc[q];
  }
  __shared__ float sred[4][8];
  float red[NUM_QUEUES];
#pragma unroll
  for (int q = 0; q < NUM_QUEUES; ++q) {
    float m = acc[q];   // inactive lanes duplicate clause 49999 (harmless for max)
#pragma unroll
    for (int o = 32; o > 0; o >>= 1) m = fmaxf(m, __shfl_xor(m, o, 64));
    red[q] = m;
  }
  if ((t & 63) == 0) {
    int w = t >> 6;
#pragma unroll
    for (int q = 0; q < NUM_QUEUES; ++q) sred[w][q] = red[q];
  }
  __syncthreads();
  if (t < NUM_QUEUES) {
    float m = fmaxf(fmaxf(sred[0][t], sred[1][t]), fmaxf(sred[2][t], sred[3][t]));
    atomicMax(&rowmax_i[t], enc_f(m));
  }
}

// Block (q,g): pin e = exp(l-M) for ALL 50000 clauses of queue q in LDS (bf16),
// then sweep 8 steps reading ONLY the mask (single pass over the 102 MB mask
// total across the grid). a = l-M reconstructed as ln(e). No logits re-reads
// -> no L2 thrash -> no 410 MB L3 stream. Writes loss[s] directly.
__global__ __launch_bounds__(512) void k_step(const float* __restrict__ logits,
    const int* __restrict__ rowmax_i, const void* __restrict__ maskv,
    const float* __restrict__ rewards, const int* __restrict__ si,
    float* __restrict__ loss) {
  extern __shared__ unsigned short Elds[];   // [50000] bf16 e
  __shared__ float sZ[8], sS[8], sC[8];
  int bid = blockIdx.x, t = threadIdx.x;
  int q = bid >> 5, g = bid & 31;            // queue_idx = s % 8 (reference setup)
  // mask dtype self-detect (first 512 words, L2-hot; per-wave __any)
  const unsigned* mw0 = (const unsigned*)maskv;
  bool bytemask = __any(mw0[t] > 1u);
  float M = dec_f(rowmax_i[q]);
  const float* lrow = logits + (size_t)q * N_CLAUSES;

  // ---- fill LDS: e[n] = bf16(exp(l[n]-M)), 2 clauses/thread/iter ----
#pragma unroll 2
  for (int it = 0; it < 48; ++it) {
    int idx = it * 1024 + 2 * t;
    float2 l = *(const float2*)(lrow + idx);
    float e0 = __expf(l.x - M), e1 = __expf(l.y - M);
    unsigned p = ((__float_as_uint(e0) + 0x8000u) >> 16) |
                 (((__float_as_uint(e1) + 0x8000u) >> 16) << 16);
    *(unsigned*)(&Elds[idx]) = p;
  }
  if (t < 424) {
    int idx = 49152 + 2 * t;
    float2 l = *(const float2*)(lrow + idx);
    float e0 = __expf(l.x - M), e1 = __expf(l.y - M);
    unsigned p = ((__float_as_uint(e0) + 0x8000u) >> 16) |
                 (((__float_as_uint(e1) + 0x8000u) >> 16) << 16);
    *(unsigned*)(&Elds[idx]) = p;
  }
  __syncthreads();

  // ---- 8 steps: s = q + 8*(g*8 + i) ----
  for (int i8 = 0; i8 < 8; ++i8) {
    int s = q + 8 * (g * 8 + i8);
    float z = 0.f, s1 = 0.f, c = 0.f;
    if (bytemask) {
      const unsigned* mrow =
          (const unsigned*)((const unsigned char*)maskv + (size_t)s * N_CLAUSES);
#pragma unroll 2
      for (int it = 0; it < 25; ++it) {
        int widx = it * 512 + t;
        if (it == 24 && t >= 212) break;    // 12500 = 24*512 + 212
        unsigned m = mrow[widx];
        unsigned p0 = *(const unsigned*)(&Elds[widx * 4]);
        unsigned p1 = *(const unsigned*)(&Elds[widx * 4 + 2]);
        float e0 = __uint_as_float(p0 << 16);
        float e1 = __uint_as_float(p0 & 0xffff0000u);
        float e2 = __uint_as_float(p1 << 16);
        float e3 = __uint_as_float(p1 & 0xffff0000u);
        float b0 = (m & 0x000000ffu) ? 1.f : 0.f;
        float b1 = (m & 0x0000ff00u) ? 1.f : 0.f;
        float b2 = (m & 0x00ff0000u) ? 1.f : 0.f;
        float b3 = (m & 0xff000000u) ? 1.f : 0.f;
        float a0 = __logf(fmaxf(e0, 1e-37f));
        float a1 = __logf(fmaxf(e1, 1e-37f));
        float a2 = __logf(fmaxf(e2, 1e-37f));
        float a3 = __logf(fmaxf(e3, 1e-37f));
        z  = fmaf(b0, e0, z);        z  = fmaf(b1, e1, z);
        z  = fmaf(b2, e2, z);        z  = fmaf(b3, e3, z);
        s1 = fmaf(b0, e0 * a0, s1);  s1 = fmaf(b1, e1 * a1, s1);
        s1 = fmaf(b2, e2 * a2, s1);  s1 = fmaf(b3, e3 * a3, s1);
        c += (b0 + b1) + (b2 + b3);
      }
    } else {
      const v4u* mrow = (const v4u*)((const int*)maskv + (size_t)s * N_CLAUSES);
#pragma unroll 2
      for (int it = 0; it < 25; ++it) {
        int widx = it * 512 + t;
        if (it == 24 && t >= 212) break;
        v4u m = mrow[widx];
        unsigned p0 = *(const unsigned*)(&Elds[widx * 4]);
        unsigned p1 = *(const unsigned*)(&Elds[widx * 4 + 2]);
        float e0 = __uint_as_float(p0 << 16);
        float e1 = __uint_as_float(p0 & 0xffff0000u);
        float e2 = __uint_as_float(p1 << 16);
        float e3 = __uint_as_float(p1 & 0xffff0000u);
        float b0 = m.x ? 1.f : 0.f;
        float b1 = m.y ? 1.f : 0.f;
        float b2 = m.z ? 1.f : 0.f;
        float b3 = m.w ? 1.f : 0.f;
        float a0 = __logf(fmaxf(e0, 1e-37f));
        float a1 = __logf(fmaxf(e1, 1e-37f));
        float a2 = __logf(fmaxf(e2, 1e-37f));
        float a3 = __logf(fmaxf(e3, 1e-37f));
        z  = fmaf(b0, e0, z);        z  = fmaf(b1, e1, z);
        z  = fmaf(b2, e2, z);        z  = fmaf(b3, e3, z);
        s1 = fmaf(b0, e0 * a0, s1);  s1 = fmaf(b1, e1 * a1, s1);
        s1 = fmaf(b2, e2 * a2, s1);  s1 = fmaf(b3, e3 * a3, s1);
        c += (b0 + b1) + (b2 + b3);
      }
    }
#pragma unroll
    for (int o = 32; o > 0; o >>= 1) {
      z += __shfl_xor(z, o, 64);
      s1 += __shfl_xor(s1, o, 64);
      c += __shfl_xor(c, o, 64);
    }
    int w = t >> 6;
    if ((t & 63) == 0) { sZ[w] = z; sS[w] = s1; sC[w] = c; }
    __syncthreads();
    if (t == 0) {
      float Z = ((sZ[0] + sZ[1]) + (sZ[2] + sZ[3])) + ((sZ[4] + sZ[5]) + (sZ[6] + sZ[7]));
      float S = ((sS[0] + sS[1]) + (sS[2] + sS[3])) + ((sS[4] + sS[5]) + (sS[6] + sS[7]));
      float C = ((sC[0] + sC[1]) + (sC[2] + sC[3])) + ((sC[4] + sC[5]) + (sC[6] + sC[7]));
      float ssel = lrow[si[s]];
      float logZ = logf(Z);
      float ce = logZ - (ssel - M);            // = -log_softmax[sel]
      float me = (S / Z - logZ) / logf(C);     // normalized minus-entropy
      loss[s] = rewards[s] * ce + ENTROPY_COEF * me;
    }
    __syncthreads();   // protect sZ/sS/sC reuse next step
  }
}

__global__ __launch_bounds__(256) void k_sum(const float* __restrict__ loss,
                                             float* __restrict__ out) {
  int tid = threadIdx.x;
  float v = 0.f;
  for (int i = tid; i < NUM_STEPS; i += 256) v += loss[i];
#pragma unroll
  for (int o = 32; o > 0; o >>= 1) v += __shfl_xor(v, o, 64);
  __shared__ float sv[4];
  if ((tid & 63) == 0) sv[tid >> 6] = v;
  __syncthreads();
  if (tid == 0) out[0] = sv[0] + sv[1] + sv[2] + sv[3];
}

extern "C" void kernel_launch(void* const* d_in, const int* in_sizes, int n_in,
                              void* d_out, int out_size, void* d_ws, size_t ws_size,
                              hipStream_t stream) {
  const float* fv      = (const float*)d_in[0];
  const float* W1      = (const float*)d_in[1];
  const float* b1      = (const float*)d_in[2];
  const float* W2      = (const float*)d_in[3];
  const float* b2      = (const float*)d_in[4];
  const float* keys    = (const float*)d_in[5];
  const float* rewards = (const float*)d_in[6];
  const void*  mask    = d_in[7];
  const int*   sel_i   = (const int*)d_in[9];
  float* out = (float*)d_out;
  float* ws  = (float*)d_ws;

  float* logits   = ws + WS_LOGITS;
  int*   rowmax_i = (int*)(ws + WS_ROWMAX);
  float* K2T      = ws + WS_K2T;
  float* cq       = ws + WS_CQ;
  float* W1T      = ws + WS_W1T;
  float* loss     = ws + WS_LOSS;

  // allow >48KB dynamic LDS (no-op if already permitted; host-side, capture-safe)
  static bool attr_set = false;
  if (!attr_set) {
    hipFuncSetAttribute((const void*)k_step,
                        hipFuncAttributeMaxDynamicSharedMemorySize, LDS_BYTES);
    attr_set = true;
  }

  hipLaunchKernelGGL(k_prep, dim3(1), dim3(1024), 0, stream,
                     W1, b2, W2, keys, W1T, K2T, cq, rowmax_i);
  hipLaunchKernelGGL(k_logits, dim3((N_CLAUSES + 255) / 256), dim3(256), 0, stream,
                     fv, b1, W1T, K2T, cq, logits, rowmax_i);
  hipLaunchKernelGGL(k_step, dim3(256), dim3(512), LDS_BYTES, stream,
                     logits, rowmax_i, mask, rewards, sel_i, loss);
  hipLaunchKernelGGL(k_sum, dim3(1), dim3(256), 0, stream, loss, out);
}

// Round 11
// 198.021 us; speedup vs baseline: 1.3098x; 1.3098x over previous
//
#include <hip/hip_runtime.h>

#define N_CLAUSES 50000
#define FEAT_DIM 64
#define EMBED_DIM 128
#define NUM_QUEUES 8
#define NUM_STEPS 2048
#define ENTROPY_COEF 0.1f

#define NSG 32        // step-groups per queue (8 steps each): 8*32*8 = 2048
#define NCHK 10       // clause chunks
#define WPC 1250      // words per chunk (12500 words/row, 4 clauses/word)

typedef unsigned int v4u __attribute__((ext_vector_type(4)));

// ---------------- workspace layout (float units) ----------------
#define WS_LOGITS 0                 // [8][50000]
#define WS_ROWMAX 400000            // [8] int-encoded max
#define WS_K2T    400008            // [128][8]
#define WS_CQ     401032            // [8]
#define WS_W1T    401040            // [128][64]
#define WS_PART   409248            // [2048][10] float4
#define WS_LOSS   (WS_PART + NUM_STEPS * NCHK * 4)   // [2048]

// order-preserving float<->int encode for atomicMax on signed int
__device__ inline int enc_f(float f) {
  int b = __float_as_int(f);
  return b >= 0 ? b : (b ^ 0x7FFFFFFF);
}
__device__ inline float dec_f(int k) {
  return __int_as_float(k >= 0 ? k : (k ^ 0x7FFFFFFF));
}

__global__ __launch_bounds__(1024) void k_prep(const float* __restrict__ W1,
    const float* __restrict__ b2, const float* __restrict__ W2,
    const float* __restrict__ keys, float* __restrict__ W1T,
    float* __restrict__ K2T, float* __restrict__ cq, int* __restrict__ rowmax_i) {
  int tid = threadIdx.x;
  {
    int q = tid >> 7, j = tid & 127;
    float a = 0.f;
    for (int e = 0; e < EMBED_DIM; ++e)
      a = fmaf(W2[j * EMBED_DIM + e], keys[q * EMBED_DIM + e], a);
    K2T[j * 8 + q] = a;
  }
  if (tid < NUM_QUEUES) {
    float a = 0.f;
    for (int e = 0; e < EMBED_DIM; ++e)
      a = fmaf(b2[e], keys[tid * EMBED_DIM + e], a);
    cq[tid] = a;
    rowmax_i[tid] = (int)0x80000000;   // INT_MIN
  }
  for (int i = tid; i < FEAT_DIM * EMBED_DIM; i += 1024) {
    int j = i >> 6, f = i & 63;
    W1T[j * 64 + f] = W1[f * EMBED_DIM + j];
  }
}

// logits[q][n] = relu(fv[n]@W1 + b1) . K2[q] + cq[q]; fused per-queue row-max.
__global__ __launch_bounds__(256) void k_logits(const float* __restrict__ fv,
    const float* __restrict__ b1, const float* __restrict__ W1T,
    const float* __restrict__ K2T, const float* __restrict__ cq,
    float* __restrict__ logits, int* __restrict__ rowmax_i) {
  int t = threadIdx.x;
  int n = blockIdx.x * 256 + t;
  bool act = n < N_CLAUSES;
  int nn = act ? n : (N_CLAUSES - 1);
  float r[FEAT_DIM];
  const float4* fp = (const float4*)(fv + (size_t)nn * FEAT_DIM);
#pragma unroll
  for (int i = 0; i < FEAT_DIM / 4; ++i) {
    float4 v = fp[i];
    r[4 * i] = v.x; r[4 * i + 1] = v.y; r[4 * i + 2] = v.z; r[4 * i + 3] = v.w;
  }
  float acc[NUM_QUEUES];
#pragma unroll
  for (int q = 0; q < NUM_QUEUES; ++q) acc[q] = cq[q];
#pragma unroll 4
  for (int j = 0; j < EMBED_DIM; ++j) {
    const float* w = W1T + j * 64;   // wave-uniform -> scalar loads
    float t0 = 0.f, t1 = 0.f, t2 = 0.f, t3 = 0.f;
#pragma unroll
    for (int f = 0; f < FEAT_DIM; f += 4) {
      t0 = fmaf(r[f],     w[f],     t0);
      t1 = fmaf(r[f + 1], w[f + 1], t1);
      t2 = fmaf(r[f + 2], w[f + 2], t2);
      t3 = fmaf(r[f + 3], w[f + 3], t3);
    }
    float tt = fmaxf((t0 + t1) + (t2 + t3) + b1[j], 0.f);
    const float* k2 = K2T + j * 8;
#pragma unroll
    for (int q = 0; q < NUM_QUEUES; ++q) acc[q] = fmaf(tt, k2[q], acc[q]);
  }
  if (act) {
#pragma unroll
    for (int q = 0; q < NUM_QUEUES; ++q)
      logits[(size_t)q * N_CLAUSES + n] = acc[q];
  }
  __shared__ float sred[4][8];
  float red[NUM_QUEUES];
#pragma unroll
  for (int q = 0; q < NUM_QUEUES; ++q) {
    float m = acc[q];   // inactive lanes duplicate clause 49999 (harmless for max)
#pragma unroll
    for (int o = 32; o > 0; o >>= 1) m = fmaxf(m, __shfl_xor(m, o, 64));
    red[q] = m;
  }
  if ((t & 63) == 0) {
    int w = t >> 6;
#pragma unroll
    for (int q = 0; q < NUM_QUEUES; ++q) sred[w][q] = red[q];
  }
  __syncthreads();
  if (t < NUM_QUEUES) {
    float m = fmaxf(fmaxf(sred[0][t], sred[1][t]), fmaxf(sred[2][t], sred[3][t]));
    atomicMax(&rowmax_i[t], enc_f(m));
  }
}

// Block (c,q,g): 8 steps s = q+64g+8j share one sweep over chunk c's 1250 words.
// Per word-iteration: ONE logits float4 + exp (amortized 8x) + EIGHT independent
// mask loads (scalar row bases, per-lane offset) -> 9 loads in flight/thread.
// Accumulators in registers; reduction covers ALL chunk clauses for every step.
__global__ __launch_bounds__(256) void k_step(const float* __restrict__ logits,
    const int* __restrict__ rowmax_i, const void* __restrict__ maskv,
    float4* __restrict__ part) {
  int c = blockIdx.x, q = blockIdx.y, g = blockIdx.z;
  int t = threadIdx.x;
  // mask dtype self-detect (first 1024 words, L2-hot; per-wave __any)
  const unsigned* mw0 = (const unsigned*)maskv;
  bool bytemask = __any((mw0[t] > 1u) | (mw0[t + 256] > 1u) |
                        (mw0[t + 512] > 1u) | (mw0[t + 768] > 1u));
  float M = dec_f(rowmax_i[q]);
  const float4* lrow4 = (const float4*)(logits + (size_t)q * N_CLAUSES);
  int wbase = c * WPC;

  float z[8], s1[8];
  int cnt[8];
#pragma unroll
  for (int j = 0; j < 8; ++j) { z[j] = 0.f; s1[j] = 0.f; cnt[j] = 0; }

  if (bytemask) {
    const unsigned* mr[8];
#pragma unroll
    for (int j = 0; j < 8; ++j)
      mr[j] = (const unsigned*)((const unsigned char*)maskv +
                                (size_t)(q + 64 * g + 8 * j) * N_CLAUSES);
    auto body = [&](int idx) {
      float4 l = lrow4[idx];
      unsigned m[8];
#pragma unroll
      for (int j = 0; j < 8; ++j) m[j] = mr[j][idx];   // 8 independent loads
      float a0 = l.x - M, a1 = l.y - M, a2 = l.z - M, a3 = l.w - M;
      float e0 = __expf(a0), e1 = __expf(a1), e2 = __expf(a2), e3 = __expf(a3);
      float ea0 = e0 * a0, ea1 = e1 * a1, ea2 = e2 * a2, ea3 = e3 * a3;
#pragma unroll
      for (int j = 0; j < 8; ++j) {
        unsigned mm = m[j];
        float b0 = (mm & 0x000000ffu) ? 1.f : 0.f;
        float b1 = (mm & 0x0000ff00u) ? 1.f : 0.f;
        float b2 = (mm & 0x00ff0000u) ? 1.f : 0.f;
        float b3 = (mm & 0xff000000u) ? 1.f : 0.f;
        z[j]  = fmaf(b0, e0,  fmaf(b1, e1,  fmaf(b2, e2,  fmaf(b3, e3,  z[j]))));
        s1[j] = fmaf(b0, ea0, fmaf(b1, ea1, fmaf(b2, ea2, fmaf(b3, ea3, s1[j]))));
        cnt[j] += __popc(mm & 0x01010101u);
      }
    };
#pragma unroll 2
    for (int it = 0; it < 4; ++it) body(wbase + it * 256 + t);
    if (t < WPC - 1024) body(wbase + 1024 + t);          // tail: 226 threads
  } else {
    const v4u* mr[8];
#pragma unroll
    for (int j = 0; j < 8; ++j)
      mr[j] = (const v4u*)((const int*)maskv +
                           (size_t)(q + 64 * g + 8 * j) * N_CLAUSES);
    auto body = [&](int idx) {
      float4 l = lrow4[idx];
      float a0 = l.x - M, a1 = l.y - M, a2 = l.z - M, a3 = l.w - M;
      float e0 = __expf(a0), e1 = __expf(a1), e2 = __expf(a2), e3 = __expf(a3);
      float ea0 = e0 * a0, ea1 = e1 * a1, ea2 = e2 * a2, ea3 = e3 * a3;
#pragma unroll
      for (int j = 0; j < 8; ++j) {
        v4u m = mr[j][idx];
        float b0 = m.x ? 1.f : 0.f;
        float b1 = m.y ? 1.f : 0.f;
        float b2 = m.z ? 1.f : 0.f;
        float b3 = m.w ? 1.f : 0.f;
        z[j]  = fmaf(b0, e0,  fmaf(b1, e1,  fmaf(b2, e2,  fmaf(b3, e3,  z[j]))));
        s1[j] = fmaf(b0, ea0, fmaf(b1, ea1, fmaf(b2, ea2, fmaf(b3, ea3, s1[j]))));
        cnt[j] += (m.x ? 1 : 0) + (m.y ? 1 : 0) + (m.z ? 1 : 0) + (m.w ? 1 : 0);
      }
    };
    for (int it = 0; it < 4; ++it) body(wbase + it * 256 + t);
    if (t < WPC - 1024) body(wbase + 1024 + t);
  }

  // per-wave butterfly for all 8 steps, then cross-wave via LDS
  float cf[8];
#pragma unroll
  for (int j = 0; j < 8; ++j) {
    cf[j] = (float)cnt[j];
#pragma unroll
    for (int o = 32; o > 0; o >>= 1) {
      z[j]  += __shfl_xor(z[j], o, 64);
      s1[j] += __shfl_xor(s1[j], o, 64);
      cf[j] += __shfl_xor(cf[j], o, 64);
    }
  }
  __shared__ float sZ[4][8], sS[4][8], sC[4][8];
  int w = t >> 6;
  if ((t & 63) == 0) {
#pragma unroll
    for (int j = 0; j < 8; ++j) { sZ[w][j] = z[j]; sS[w][j] = s1[j]; sC[w][j] = cf[j]; }
  }
  __syncthreads();
  if (t < 8) {
    int j = t;
    int s = q + 64 * g + 8 * j;
    part[(size_t)s * NCHK + c] =
        make_float4((sZ[0][j] + sZ[1][j]) + (sZ[2][j] + sZ[3][j]),
                    (sS[0][j] + sS[1][j]) + (sS[2][j] + sS[3][j]),
                    (sC[0][j] + sC[1][j]) + (sC[2][j] + sC[3][j]), 0.f);
  }
}

// one thread per step: combine 10 chunk partials, finish per-step loss
__global__ __launch_bounds__(256) void k_red(const float4* __restrict__ part,
    const float* __restrict__ logits, const int* __restrict__ rowmax_i,
    const float* __restrict__ rewards, const int* __restrict__ qi,
    const int* __restrict__ si, float* __restrict__ loss) {
  int s = blockIdx.x * 256 + threadIdx.x;
  float z = 0.f, s1 = 0.f, c = 0.f;
#pragma unroll
  for (int e = 0; e < NCHK; ++e) {
    float4 p = part[(size_t)s * NCHK + e];
    z += p.x; s1 += p.y; c += p.z;
  }
  int q = qi[s];
  float M = dec_f(rowmax_i[q]);
  float ssel = logits[(size_t)q * N_CLAUSES + si[s]];
  float logZ = logf(z);
  float ce = logZ - (ssel - M);            // = -log_softmax[sel]
  float me = (s1 / z - logZ) / logf(c);    // normalized minus-entropy
  loss[s] = rewards[s] * ce + ENTROPY_COEF * me;
}

__global__ __launch_bounds__(256) void k_sum(const float* __restrict__ loss,
                                             float* __restrict__ out) {
  int tid = threadIdx.x;
  float v = 0.f;
  for (int i = tid; i < NUM_STEPS; i += 256) v += loss[i];
#pragma unroll
  for (int o = 32; o > 0; o >>= 1) v += __shfl_xor(v, o, 64);
  __shared__ float sv[4];
  if ((tid & 63) == 0) sv[tid >> 6] = v;
  __syncthreads();
  if (tid == 0) out[0] = sv[0] + sv[1] + sv[2] + sv[3];
}

extern "C" void kernel_launch(void* const* d_in, const int* in_sizes, int n_in,
                              void* d_out, int out_size, void* d_ws, size_t ws_size,
                              hipStream_t stream) {
  const float* fv      = (const float*)d_in[0];
  const float* W1      = (const float*)d_in[1];
  const float* b1      = (const float*)d_in[2];
  const float* W2      = (const float*)d_in[3];
  const float* b2      = (const float*)d_in[4];
  const float* keys    = (const float*)d_in[5];
  const float* rewards = (const float*)d_in[6];
  const void*  mask    = d_in[7];
  const int*   queue_i = (const int*)d_in[8];
  const int*   sel_i   = (const int*)d_in[9];
  float* out = (float*)d_out;
  float* ws  = (float*)d_ws;

  float*  logits   = ws + WS_LOGITS;
  int*    rowmax_i = (int*)(ws + WS_ROWMAX);
  float*  K2T      = ws + WS_K2T;
  float*  cq       = ws + WS_CQ;
  float*  W1T      = ws + WS_W1T;
  float4* part     = (float4*)(ws + WS_PART);
  float*  loss     = ws + WS_LOSS;

  hipLaunchKernelGGL(k_prep, dim3(1), dim3(1024), 0, stream,
                     W1, b2, W2, keys, W1T, K2T, cq, rowmax_i);
  hipLaunchKernelGGL(k_logits, dim3((N_CLAUSES + 255) / 256), dim3(256), 0, stream,
                     fv, b1, W1T, K2T, cq, logits, rowmax_i);
  hipLaunchKernelGGL(k_step, dim3(NCHK, NUM_QUEUES, NSG), dim3(256), 0, stream,
                     logits, rowmax_i, mask, part);
  hipLaunchKernelGGL(k_red, dim3(NUM_STEPS / 256), dim3(256), 0, stream,
                     part, logits, rowmax_i, rewards, queue_i, sel_i, loss);
  hipLaunchKernelGGL(k_sum, dim3(1), dim3(256), 0, stream, loss, out);
}

// Round 12
// 193.358 us; speedup vs baseline: 1.3414x; 1.0241x over previous
//
#include <hip/hip_runtime.h>

#define N_CLAUSES 50000
#define FEAT_DIM 64
#define EMBED_DIM 128
#define NUM_QUEUES 8
#define NUM_STEPS 2048
#define ENTROPY_COEF 0.1f

#define NSG 32        // step-groups per queue (8 steps each): 8*32*8 = 2048
#define NCHK 10       // clause chunks
#define WPC 1250      // words per chunk (12500 words/row, 4 clauses/word)

typedef unsigned int v4u __attribute__((ext_vector_type(4)));

// ---------------- workspace layout (float units) ----------------
#define WS_LOGITS 0                 // [8][50000]
#define WS_ROWMAX 400000            // [8] int-encoded max
#define WS_K2T    400008            // [128][8]
#define WS_CQ     401032            // [8]
#define WS_W1T    401040            // [128][64]
#define WS_PART   409248            // [2048][10] float4
#define WS_LOSS   (WS_PART + NUM_STEPS * NCHK * 4)   // [2048]

// order-preserving float<->int encode for atomicMax on signed int
__device__ inline int enc_f(float f) {
  int b = __float_as_int(f);
  return b >= 0 ? b : (b ^ 0x7FFFFFFF);
}
__device__ inline float dec_f(int k) {
  return __int_as_float(k >= 0 ? k : (k ^ 0x7FFFFFFF));
}

// PARALLEL + COALESCED prep (was: 1 block, uncoalesced lane-stride-512B loads
// serializing one CU's TA for up to ~100 µs).
// b<8:    K2T[:,q] GEMV — keys row in LDS, wave-per-row, coalesced W2 reads.
// b<40:   W1T transpose — coalesced W1 reads.
// b==40:  cq + rowmax init.
__global__ __launch_bounds__(256) void k_prep(const float* __restrict__ W1,
    const float* __restrict__ b2, const float* __restrict__ W2,
    const float* __restrict__ keys, float* __restrict__ W1T,
    float* __restrict__ K2T, float* __restrict__ cq, int* __restrict__ rowmax_i) {
  int b = blockIdx.x, t = threadIdx.x;
  if (b < 8) {
    int q = b;
    __shared__ float kq[EMBED_DIM];
    if (t < EMBED_DIM) kq[t] = keys[q * EMBED_DIM + t];
    __syncthreads();
    int w = t >> 6, lane = t & 63;
    for (int j = w; j < EMBED_DIM; j += 4) {
      const float* row = W2 + j * EMBED_DIM;
      float a = fmaf(row[lane], kq[lane], row[lane + 64] * kq[lane + 64]);
#pragma unroll
      for (int o = 32; o > 0; o >>= 1) a += __shfl_xor(a, o, 64);
      if (lane == 0) K2T[j * 8 + q] = a;
    }
  } else if (b < 40) {
    int i = (b - 8) * 256 + t;          // i = f*128 + j  (coalesced W1 read)
    int f = i >> 7, j = i & 127;
    W1T[j * 64 + f] = W1[i];
  } else {
    if (t < NUM_QUEUES) {
      float a = 0.f;
      for (int e = 0; e < EMBED_DIM; ++e)
        a = fmaf(b2[e], keys[t * EMBED_DIM + e], a);
      cq[t] = a;
      rowmax_i[t] = (int)0x80000000;    // INT_MIN
    }
  }
}

// logits[q][n] = relu(fv[n]@W1 + b1) . K2[q] + cq[q]; fused per-queue row-max.
__global__ __launch_bounds__(256) void k_logits(const float* __restrict__ fv,
    const float* __restrict__ b1, const float* __restrict__ W1T,
    const float* __restrict__ K2T, const float* __restrict__ cq,
    float* __restrict__ logits, int* __restrict__ rowmax_i) {
  int t = threadIdx.x;
  int n = blockIdx.x * 256 + t;
  bool act = n < N_CLAUSES;
  int nn = act ? n : (N_CLAUSES - 1);
  float r[FEAT_DIM];
  const float4* fp = (const float4*)(fv + (size_t)nn * FEAT_DIM);
#pragma unroll
  for (int i = 0; i < FEAT_DIM / 4; ++i) {
    float4 v = fp[i];
    r[4 * i] = v.x; r[4 * i + 1] = v.y; r[4 * i + 2] = v.z; r[4 * i + 3] = v.w;
  }
  float acc[NUM_QUEUES];
#pragma unroll
  for (int q = 0; q < NUM_QUEUES; ++q) acc[q] = cq[q];
#pragma unroll 4
  for (int j = 0; j < EMBED_DIM; ++j) {
    const float* w = W1T + j * 64;   // wave-uniform -> scalar loads
    float t0 = 0.f, t1 = 0.f, t2 = 0.f, t3 = 0.f;
#pragma unroll
    for (int f = 0; f < FEAT_DIM; f += 4) {
      t0 = fmaf(r[f],     w[f],     t0);
      t1 = fmaf(r[f + 1], w[f + 1], t1);
      t2 = fmaf(r[f + 2], w[f + 2], t2);
      t3 = fmaf(r[f + 3], w[f + 3], t3);
    }
    float tt = fmaxf((t0 + t1) + (t2 + t3) + b1[j], 0.f);
    const float* k2 = K2T + j * 8;
#pragma unroll
    for (int q = 0; q < NUM_QUEUES; ++q) acc[q] = fmaf(tt, k2[q], acc[q]);
  }
  if (act) {
#pragma unroll
    for (int q = 0; q < NUM_QUEUES; ++q)
      logits[(size_t)q * N_CLAUSES + n] = acc[q];
  }
  __shared__ float sred[4][8];
  float red[NUM_QUEUES];
#pragma unroll
  for (int q = 0; q < NUM_QUEUES; ++q) {
    float m = acc[q];   // inactive lanes duplicate clause 49999 (harmless for max)
#pragma unroll
    for (int o = 32; o > 0; o >>= 1) m = fmaxf(m, __shfl_xor(m, o, 64));
    red[q] = m;
  }
  if ((t & 63) == 0) {
    int w = t >> 6;
#pragma unroll
    for (int q = 0; q < NUM_QUEUES; ++q) sred[w][q] = red[q];
  }
  __syncthreads();
  if (t < NUM_QUEUES) {
    float m = fmaxf(fmaxf(sred[0][t], sred[1][t]), fmaxf(sred[2][t], sred[3][t]));
    atomicMax(&rowmax_i[t], enc_f(m));
  }
}

// Block (c,q,g): 8 steps s = q+64g+8j share one sweep over chunk c's 1250 words.
__global__ __launch_bounds__(256) void k_step(const float* __restrict__ logits,
    const int* __restrict__ rowmax_i, const void* __restrict__ maskv,
    float4* __restrict__ part) {
  int c = blockIdx.x, q = blockIdx.y, g = blockIdx.z;
  int t = threadIdx.x;
  const unsigned* mw0 = (const unsigned*)maskv;
  bool bytemask = __any((mw0[t] > 1u) | (mw0[t + 256] > 1u) |
                        (mw0[t + 512] > 1u) | (mw0[t + 768] > 1u));
  float M = dec_f(rowmax_i[q]);
  const float4* lrow4 = (const float4*)(logits + (size_t)q * N_CLAUSES);
  int wbase = c * WPC;

  float z[8], s1[8];
  int cnt[8];
#pragma unroll
  for (int j = 0; j < 8; ++j) { z[j] = 0.f; s1[j] = 0.f; cnt[j] = 0; }

  if (bytemask) {
    const unsigned* mr[8];
#pragma unroll
    for (int j = 0; j < 8; ++j)
      mr[j] = (const unsigned*)((const unsigned char*)maskv +
                                (size_t)(q + 64 * g + 8 * j) * N_CLAUSES);
    auto body = [&](int idx) {
      float4 l = lrow4[idx];
      unsigned m[8];
#pragma unroll
      for (int j = 0; j < 8; ++j) m[j] = mr[j][idx];   // 8 independent loads
      float a0 = l.x - M, a1 = l.y - M, a2 = l.z - M, a3 = l.w - M;
      float e0 = __expf(a0), e1 = __expf(a1), e2 = __expf(a2), e3 = __expf(a3);
      float ea0 = e0 * a0, ea1 = e1 * a1, ea2 = e2 * a2, ea3 = e3 * a3;
#pragma unroll
      for (int j = 0; j < 8; ++j) {
        unsigned mm = m[j];
        float b0 = (mm & 0x000000ffu) ? 1.f : 0.f;
        float b1 = (mm & 0x0000ff00u) ? 1.f : 0.f;
        float b2 = (mm & 0x00ff0000u) ? 1.f : 0.f;
        float b3 = (mm & 0xff000000u) ? 1.f : 0.f;
        z[j]  = fmaf(b0, e0,  fmaf(b1, e1,  fmaf(b2, e2,  fmaf(b3, e3,  z[j]))));
        s1[j] = fmaf(b0, ea0, fmaf(b1, ea1, fmaf(b2, ea2, fmaf(b3, ea3, s1[j]))));
        cnt[j] += __popc(mm & 0x01010101u);
      }
    };
#pragma unroll 2
    for (int it = 0; it < 4; ++it) body(wbase + it * 256 + t);
    if (t < WPC - 1024) body(wbase + 1024 + t);          // tail: 226 threads
  } else {
    const v4u* mr[8];
#pragma unroll
    for (int j = 0; j < 8; ++j)
      mr[j] = (const v4u*)((const int*)maskv +
                           (size_t)(q + 64 * g + 8 * j) * N_CLAUSES);
    auto body = [&](int idx) {
      float4 l = lrow4[idx];
      float a0 = l.x - M, a1 = l.y - M, a2 = l.z - M, a3 = l.w - M;
      float e0 = __expf(a0), e1 = __expf(a1), e2 = __expf(a2), e3 = __expf(a3);
      float ea0 = e0 * a0, ea1 = e1 * a1, ea2 = e2 * a2, ea3 = e3 * a3;
#pragma unroll
      for (int j = 0; j < 8; ++j) {
        v4u m = mr[j][idx];
        float b0 = m.x ? 1.f : 0.f;
        float b1 = m.y ? 1.f : 0.f;
        float b2 = m.z ? 1.f : 0.f;
        float b3 = m.w ? 1.f : 0.f;
        z[j]  = fmaf(b0, e0,  fmaf(b1, e1,  fmaf(b2, e2,  fmaf(b3, e3,  z[j]))));
        s1[j] = fmaf(b0, ea0, fmaf(b1, ea1, fmaf(b2, ea2, fmaf(b3, ea3, s1[j]))));
        cnt[j] += (m.x ? 1 : 0) + (m.y ? 1 : 0) + (m.z ? 1 : 0) + (m.w ? 1 : 0);
      }
    };
    for (int it = 0; it < 4; ++it) body(wbase + it * 256 + t);
    if (t < WPC - 1024) body(wbase + 1024 + t);
  }

  float cf[8];
#pragma unroll
  for (int j = 0; j < 8; ++j) {
    cf[j] = (float)cnt[j];
#pragma unroll
    for (int o = 32; o > 0; o >>= 1) {
      z[j]  += __shfl_xor(z[j], o, 64);
      s1[j] += __shfl_xor(s1[j], o, 64);
      cf[j] += __shfl_xor(cf[j], o, 64);
    }
  }
  __shared__ float sZ[4][8], sS[4][8], sC[4][8];
  int w = t >> 6;
  if ((t & 63) == 0) {
#pragma unroll
    for (int j = 0; j < 8; ++j) { sZ[w][j] = z[j]; sS[w][j] = s1[j]; sC[w][j] = cf[j]; }
  }
  __syncthreads();
  if (t < 8) {
    int j = t;
    int s = q + 64 * g + 8 * j;
    part[(size_t)s * NCHK + c] =
        make_float4((sZ[0][j] + sZ[1][j]) + (sZ[2][j] + sZ[3][j]),
                    (sS[0][j] + sS[1][j]) + (sS[2][j] + sS[3][j]),
                    (sC[0][j] + sC[1][j]) + (sC[2][j] + sC[3][j]), 0.f);
  }
}

// one thread per step: combine 10 chunk partials, finish per-step loss
__global__ __launch_bounds__(256) void k_red(const float4* __restrict__ part,
    const float* __restrict__ logits, const int* __restrict__ rowmax_i,
    const float* __restrict__ rewards, const int* __restrict__ qi,
    const int* __restrict__ si, float* __restrict__ loss) {
  int s = blockIdx.x * 256 + threadIdx.x;
  float z = 0.f, s1 = 0.f, c = 0.f;
#pragma unroll
  for (int e = 0; e < NCHK; ++e) {
    float4 p = part[(size_t)s * NCHK + e];
    z += p.x; s1 += p.y; c += p.z;
  }
  int q = qi[s];
  float M = dec_f(rowmax_i[q]);
  float ssel = logits[(size_t)q * N_CLAUSES + si[s]];
  float logZ = logf(z);
  float ce = logZ - (ssel - M);            // = -log_softmax[sel]
  float me = (s1 / z - logZ) / logf(c);    // normalized minus-entropy
  loss[s] = rewards[s] * ce + ENTROPY_COEF * me;
}

__global__ __launch_bounds__(256) void k_sum(const float* __restrict__ loss,
                                             float* __restrict__ out) {
  int tid = threadIdx.x;
  float v = 0.f;
  for (int i = tid; i < NUM_STEPS; i += 256) v += loss[i];
#pragma unroll
  for (int o = 32; o > 0; o >>= 1) v += __shfl_xor(v, o, 64);
  __shared__ float sv[4];
  if ((tid & 63) == 0) sv[tid >> 6] = v;
  __syncthreads();
  if (tid == 0) out[0] = sv[0] + sv[1] + sv[2] + sv[3];
}

extern "C" void kernel_launch(void* const* d_in, const int* in_sizes, int n_in,
                              void* d_out, int out_size, void* d_ws, size_t ws_size,
                              hipStream_t stream) {
  const float* fv      = (const float*)d_in[0];
  const float* W1      = (const float*)d_in[1];
  const float* b1      = (const float*)d_in[2];
  const float* W2      = (const float*)d_in[3];
  const float* b2      = (const float*)d_in[4];
  const float* keys    = (const float*)d_in[5];
  const float* rewards = (const float*)d_in[6];
  const void*  mask    = d_in[7];
  const int*   queue_i = (const int*)d_in[8];
  const int*   sel_i   = (const int*)d_in[9];
  float* out = (float*)d_out;
  float* ws  = (float*)d_ws;

  float*  logits   = ws + WS_LOGITS;
  int*    rowmax_i = (int*)(ws + WS_ROWMAX);
  float*  K2T      = ws + WS_K2T;
  float*  cq       = ws + WS_CQ;
  float*  W1T      = ws + WS_W1T;
  float4* part     = (float4*)(ws + WS_PART);
  float*  loss     = ws + WS_LOSS;

  hipLaunchKernelGGL(k_prep, dim3(41), dim3(256), 0, stream,
                     W1, b2, W2, keys, W1T, K2T, cq, rowmax_i);
  hipLaunchKernelGGL(k_logits, dim3((N_CLAUSES + 255) / 256), dim3(256), 0, stream,
                     fv, b1, W1T, K2T, cq, logits, rowmax_i);
  hipLaunchKernelGGL(k_step, dim3(NCHK, NUM_QUEUES, NSG), dim3(256), 0, stream,
                     logits, rowmax_i, mask, part);
  hipLaunchKernelGGL(k_red, dim3(NUM_STEPS / 256), dim3(256), 0, stream,
                     part, logits, rowmax_i, rewards, queue_i, sel_i, loss);
  hipLaunchKernelGGL(k_sum, dim3(1), dim3(256), 0, stream, loss, out);
}